// Round 11
// baseline (423.025 us; speedup 1.0000x reference)
//
#include <hip/hip_runtime.h>
#include <hip/hip_bf16.h>
#include <cstdint>

typedef unsigned short u16;
typedef __attribute__((ext_vector_type(4))) float f32x4;
typedef __attribute__((ext_vector_type(8))) short s16x8;
typedef __attribute__((ext_vector_type(4))) unsigned int u32x4;
typedef __attribute__((ext_vector_type(2))) unsigned int u32x2;
typedef __attribute__((ext_vector_type(4))) unsigned short u16x4;

#define MFMA16(a, b, c) __builtin_amdgcn_mfma_f32_16x16x32_bf16(a, b, c, 0, 0, 0)
#define GLOAD16(g, l) __builtin_amdgcn_global_load_lds((const __attribute__((address_space(1))) void*)(g), (__attribute__((address_space(3))) void*)(l), 16, 0, 0)

__device__ __forceinline__ u16 f2bf(float f) {
    union { float f; uint32_t u; } v{f};
    uint32_t r = v.u + 0x7FFF + ((v.u >> 16) & 1);
    return (u16)(r >> 16);
}

// ---------------- cast fp32 -> bf16 (vector x4) ----------------
__global__ void cast_f32_bf16(const float* __restrict__ in, u16* __restrict__ out, int n4) {
    int i = blockIdx.x * 256 + threadIdx.x;
    if (i >= n4) return;
    float4 f = ((const float4*)in)[i];
    u16x4 o = { f2bf(f.x), f2bf(f.y), f2bf(f.z), f2bf(f.w) };
    ((u16x4*)out)[i] = o;
}

// ---------------- RoPE cos/sin table: [B*S][64] ----------------
__global__ void rope_table_k(const int* __restrict__ pos, float* __restrict__ ct, float* __restrict__ st) {
    int i = blockIdx.x * 256 + threadIdx.x;  // B*S*64 = 262144
    int j = i & 63;
    int bs = i >> 6;
    float p = (float)pos[bs];
    float invf = powf(10000.0f, -(float)j * (1.0f / 64.0f));
    float ang = p * invf;
    ct[i] = cosf(ang);
    st[i] = sinf(ang);
}

// ---------------- GEMM C = A @ B^T (bf16 in, f32 out), m97-style ----------------
// 128x128 tile, BK=64, 4 waves, global_load_lds staging with pre-swizzled global src.
__global__ __launch_bounds__(256) void gemm_bt(const u16* __restrict__ A, const u16* __restrict__ Bw,
                                               float* __restrict__ C, int M, int N, int K) {
    __shared__ u16 As[128 * 64];
    __shared__ u16 Bs[128 * 64];
    const int tid = threadIdx.x;
    const int lane = tid & 63, wid = tid >> 6;
    const int g = lane >> 4, r = lane & 15;
    const size_t bm = (size_t)blockIdx.y * 128, bn = (size_t)blockIdx.x * 128;
    const int wr = (wid >> 1) * 64, wc = (wid & 1) * 64;

    const int srow = wid * 32 + (lane >> 3);
    const int schunk = (lane & 7) ^ ((lane >> 3) & 7);
    const u16* aSrc = A + (bm + srow) * (size_t)K + schunk * 8;
    const u16* bSrc = Bw + (bn + srow) * (size_t)K + schunk * 8;
    u16* aDst = As + wid * 2048;  // 32 rows * 64
    u16* bDst = Bs + wid * 2048;

    f32x4 acc[4][4] = {};
    for (int kt = 0; kt < K; kt += 64) {
#pragma unroll
        for (int j = 0; j < 4; ++j) {
            GLOAD16(aSrc + (size_t)(j * 8) * K + kt, aDst + j * 512);
            GLOAD16(bSrc + (size_t)(j * 8) * K + kt, bDst + j * 512);
        }
        __syncthreads();
        s16x8 af[4][2], bfr[4][2];
#pragma unroll
        for (int m = 0; m < 4; ++m)
#pragma unroll
            for (int kk = 0; kk < 2; ++kk) {
                int rowa = wr + m * 16 + r;
                af[m][kk] = *(const s16x8*)(As + rowa * 64 + (((kk * 4 + g) ^ (rowa & 7)) << 3));
                int rowb = wc + m * 16 + r;
                bfr[m][kk] = *(const s16x8*)(Bs + rowb * 64 + (((kk * 4 + g) ^ (rowb & 7)) << 3));
            }
#pragma unroll
        for (int m = 0; m < 4; ++m)
#pragma unroll
            for (int n = 0; n < 4; ++n) {
                acc[m][n] = MFMA16(af[m][0], bfr[n][0], acc[m][n]);
                acc[m][n] = MFMA16(af[m][1], bfr[n][1], acc[m][n]);
            }
        __syncthreads();
    }
#pragma unroll
    for (int m = 0; m < 4; ++m)
#pragma unroll
        for (int n = 0; n < 4; ++n)
#pragma unroll
            for (int i = 0; i < 4; ++i) {
                size_t row = bm + wr + m * 16 + g * 4 + i;
                size_t col = bn + wc + n * 16 + r;
                C[row * N + col] = acc[m][n][i];
            }
}

// ---------------- RoPE + scatter QKV f32 -> Qb/Kb/Vb bf16 (head-major) ----------------
__global__ void rope_scatter_k(const float* __restrict__ qkv, const float* __restrict__ ct,
                               const float* __restrict__ st, u16* __restrict__ Qb,
                               u16* __restrict__ Kb, u16* __restrict__ Vb) {
    int bs = blockIdx.y;
    int col = blockIdx.x * 256 + threadIdx.x;
    int b = bs >> 11, s = bs & 2047;
    const float* rowp = qkv + (size_t)bs * 3072;
    float x = rowp[col];
    int d = col & 127;
    if (col >= 2560) {
        int h = (col - 2560) >> 7;
        Vb[(((size_t)(b * 4 + h) * 2048 + s) << 7) + d] = f2bf(x);
    } else {
        int j = d & 63;
        float c = ct[(bs << 6) + j], sn = st[(bs << 6) + j];
        float other = rowp[(col & ~127) + (d ^ 64)];
        float res = (d < 64) ? (x * c - other * sn) : (x * c + other * sn);
        if (col < 2048) {
            int h = col >> 7;
            Qb[(((size_t)(b * 16 + h) * 2048 + s) << 7) + d] = f2bf(res);
        } else {
            int h = (col - 2048) >> 7;
            Kb[(((size_t)(b * 4 + h) * 2048 + s) << 7) + d] = f2bf(res);
        }
    }
}

// ---------------- causal flash attention (round-10 math, 2-wave/QBLK=64 blocks) ----------------
// grid: (S/64, B*NQ) = (32, 32) = 1024 blocks, 128 threads (2 waves). Wave w owns
// frag0 rows q0+w*16..+15 and frag1 rows q0+32+w*16..+15. KV tile = 64, K/V in regs
// (T14), same swizzles/softmax/P-LDS addressing as the verified round-10 kernel.
// LDS 40KB -> 4 blocks/CU (occupancy fix: grid was the binding constraint at 512).
__global__ __launch_bounds__(128, 2) void attn_k(const u16* __restrict__ Qb, const u16* __restrict__ Kb,
                                                 const u16* __restrict__ Vb, u16* __restrict__ Ob) {
    __shared__ char smem[40960];
    u16* Ksh = (u16*)smem;              // 16KB [64][128], chunk^=(row&7)
    u16* Vts = (u16*)(smem + 16384);    // 16KB [128][64], chunk^=(d&7)^((d>>3)&7)
    char* Pall = smem + 32768;          // 8KB: 4 x 2KB per (wave,frag)
    const int tid = threadIdx.x;
    const int lane = tid & 63, w = tid >> 6;   // w in {0,1}
    const int g = lane >> 4, r = lane & 15;
    const int bh = blockIdx.y;
    const int b = bh >> 4, h = bh & 15;
    const int hkv = h >> 2;
    const int qblk = gridDim.x - 1 - blockIdx.x;   // heavy blocks first
    const int q0 = qblk * 64;
    const u16* Qh = Qb + ((size_t)(b * 16 + h) << 18);
    const u16* Kh = Kb + ((size_t)(b * 4 + hkv) << 18);
    const u16* Vh = Vb + ((size_t)(b * 4 + hkv) << 18);

    const int base[2] = { q0 + w * 16, q0 + 32 + w * 16 };
    const int fmax[2] = { base[0] + 15, base[1] + 15 };

    s16x8 qf[2][4];
#pragma unroll
    for (int qq = 0; qq < 2; ++qq)
#pragma unroll
        for (int c = 0; c < 4; ++c)
            qf[qq][c] = *(const s16x8*)(Qh + (size_t)(base[qq] + r) * 128 + c * 32 + g * 8);

    f32x4 o[2][8] = {};              // per frag O^T: col q=r, row d=dsb*16+g*4+i
    float mrun[2] = {-1e30f, -1e30f};
    float lrun[2] = {0.f, 0.f};

    const int ntiles = qblk + 1;
    const int krow0 = tid >> 4, kch = tid & 15;   // K: 8 rows x 16 chunks per it (8 its)
    const int vdc = tid & 15, vkvp = tid >> 4;    // V: 8 kv-pairs x 16 d-chunks per it (4 its)

    // prefetch tile 0 into registers
    u32x4 kpr[8], var[4], vbr[4];
#pragma unroll
    for (int it = 0; it < 8; ++it)
        kpr[it] = *(const u32x4*)(Kh + (size_t)(krow0 + it * 8) * 128 + kch * 8);
#pragma unroll
    for (int it = 0; it < 4; ++it) {
        int kv2 = (vkvp + it * 8) * 2;
        var[it] = *(const u32x4*)(Vh + (size_t)kv2 * 128 + vdc * 8);
        vbr[it] = *(const u32x4*)(Vh + (size_t)(kv2 + 1) * 128 + vdc * 8);
    }

    for (int t = 0; t < ntiles; ++t) {
        const int kv0 = t * 64;
        __syncthreads();
        // write K tile from regs
#pragma unroll
        for (int it = 0; it < 8; ++it) {
            int row = krow0 + it * 8;
            *(u32x4*)((char*)Ksh + row * 256 + ((kch ^ (row & 7)) << 4)) = kpr[it];
        }
        // write V transposed from regs
#pragma unroll
        for (int it = 0; it < 4; ++it) {
            int kv2 = (vkvp + it * 8) * 2;
            const u16* p0 = (const u16*)&var[it];
            const u16* p1 = (const u16*)&vbr[it];
#pragma unroll
            for (int j = 0; j < 8; ++j) {
                int d = vdc * 8 + j;
                unsigned int val = (unsigned int)p0[j] | ((unsigned int)p1[j] << 16);
                *(unsigned int*)((char*)Vts +
                    ((d * 128 + kv2 * 2) ^ ((((d & 7) ^ ((d >> 3) & 7))) << 4))) = val;
            }
        }
        __syncthreads();
        // issue next tile's global loads (hidden under compute)
        if (t + 1 < ntiles) {
            const int kn = kv0 + 64;
#pragma unroll
            for (int it = 0; it < 8; ++it)
                kpr[it] = *(const u32x4*)(Kh + (size_t)(kn + krow0 + it * 8) * 128 + kch * 8);
#pragma unroll
            for (int it = 0; it < 4; ++it) {
                int kv2 = kn + (vkvp + it * 8) * 2;
                var[it] = *(const u32x4*)(Vh + (size_t)kv2 * 128 + vdc * 8);
                vbr[it] = *(const u32x4*)(Vh + (size_t)(kv2 + 1) * 128 + vdc * 8);
            }
        }
        // ---- QK^T: shared K fragments feed both q-frags ----
        f32x4 st4[2][4];
#pragma unroll
        for (int ts = 0; ts < 4; ++ts) {
            int row = ts * 16 + r;
            s16x8 kf[4];
#pragma unroll
            for (int c = 0; c < 4; ++c)
                kf[c] = *(const s16x8*)((const char*)Ksh + row * 256 + (((c * 4 + g) ^ (row & 7)) << 4));
            f32x4 a0 = {}, a1 = {};
            if (kv0 <= fmax[0])
#pragma unroll
                for (int c = 0; c < 4; ++c) a0 = MFMA16(kf[c], qf[0][c], a0);
            if (kv0 <= fmax[1])
#pragma unroll
                for (int c = 0; c < 4; ++c) a1 = MFMA16(kf[c], qf[1][c], a1);
            st4[0][ts] = a0;
            st4[1][ts] = a1;
        }
        // ---- per-frag online softmax + P write ----
#pragma unroll
        for (int qq = 0; qq < 2; ++qq) {
            if (kv0 > fmax[qq]) continue;   // wave-uniform, no barriers inside
            const int qg = base[qq] + r;
            float sv[16];
            float mtile = -1e30f;
#pragma unroll
            for (int ts = 0; ts < 4; ++ts)
#pragma unroll
                for (int i = 0; i < 4; ++i) {
                    int kvg = kv0 + ts * 16 + g * 4 + i;
                    float s = st4[qq][ts][i] * 0.08838834764831845f;
                    s = (kvg > qg) ? -1e30f : s;
                    sv[ts * 4 + i] = s;
                    mtile = fmaxf(mtile, s);
                }
            mtile = fmaxf(mtile, __shfl_xor(mtile, 16));
            mtile = fmaxf(mtile, __shfl_xor(mtile, 32));
            float mnew = fmaxf(mrun[qq], mtile);
            float corr = __expf(mrun[qq] - mnew);
            float psum = 0.f;
            unsigned int pw[8];
#pragma unroll
            for (int ts = 0; ts < 4; ++ts) {
                float p0 = __expf(sv[ts * 4 + 0] - mnew);
                float p1 = __expf(sv[ts * 4 + 1] - mnew);
                float p2 = __expf(sv[ts * 4 + 2] - mnew);
                float p3 = __expf(sv[ts * 4 + 3] - mnew);
                psum += (p0 + p1) + (p2 + p3);
                pw[ts * 2 + 0] = (unsigned int)f2bf(p0) | ((unsigned int)f2bf(p1) << 16);
                pw[ts * 2 + 1] = (unsigned int)f2bf(p2) | ((unsigned int)f2bf(p3) << 16);
            }
            psum += __shfl_xor(psum, 16);
            psum += __shfl_xor(psum, 32);
            lrun[qq] = lrun[qq] * corr + psum;
            mrun[qq] = mnew;
#pragma unroll
            for (int dsb = 0; dsb < 8; ++dsb)
#pragma unroll
                for (int i = 0; i < 4; ++i) o[qq][dsb][i] *= corr;
            char* pbase = Pall + (w * 2 + qq) * 2048;
#pragma unroll
            for (int ts = 0; ts < 4; ++ts) {
                int chunk = (ts * 2 + (g >> 1)) ^ (r & 7);
                u32x2 val = { pw[ts * 2], pw[ts * 2 + 1] };
                *(u32x2*)(pbase + r * 128 + chunk * 16 + (g & 1) * 8) = val;
            }
        }
        asm volatile("s_waitcnt lgkmcnt(0)" ::: "memory");
        // ---- PV: shared V fragments feed both q-frags ----
#pragma unroll
        for (int c = 0; c < 2; ++c) {
            s16x8 vf[8];
#pragma unroll
            for (int dsb = 0; dsb < 8; ++dsb) {
                int d = dsb * 16 + r;
                vf[dsb] = *(const s16x8*)((const char*)Vts + d * 128 +
                    ((((c * 4 + g) ^ (d & 7) ^ ((d >> 3) & 7))) << 4));
            }
#pragma unroll
            for (int qq = 0; qq < 2; ++qq) {
                if (kv0 > fmax[qq]) continue;
                s16x8 pf = *(const s16x8*)(Pall + (w * 2 + qq) * 2048 + r * 128 +
                                           (((c * 4 + g) ^ (r & 7)) << 4));
#pragma unroll
                for (int dsb = 0; dsb < 8; ++dsb)
                    o[qq][dsb] = MFMA16(vf[dsb], pf, o[qq][dsb]);
            }
        }
    }
    // ---- epilogue: normalize, per-(wave,frag) LDS transpose, coalesced store ----
    __syncthreads();
#pragma unroll
    for (int qq = 0; qq < 2; ++qq) {
        float linv = 1.0f / lrun[qq];
        char* obase = smem + (w * 2 + qq) * 4096;   // 4KB: [16 q][128 d] bf16
#pragma unroll
        for (int dsb = 0; dsb < 8; ++dsb)
#pragma unroll
            for (int i = 0; i < 4; ++i) {
                int d = dsb * 16 + g * 4 + i;
                *(u16*)(obase + r * 256 + d * 2) = f2bf(o[qq][dsb][i] * linv);
            }
    }
    asm volatile("s_waitcnt lgkmcnt(0)" ::: "memory");
    const int rr = lane >> 2, cbo = (lane & 3) * 32;
#pragma unroll
    for (int qq = 0; qq < 2; ++qq) {
        char* obase = smem + (w * 2 + qq) * 4096;
        size_t oidx = ((size_t)b * 2048 + base[qq] + rr) * 2048 + h * 128 + cbo;
#pragma unroll
        for (int p = 0; p < 4; ++p) {
            u32x4 vv = *(const u32x4*)(obase + rr * 256 + cbo * 2 + p * 16);
            *(u32x4*)(Ob + oidx + p * 8) = vv;
        }
    }
}

extern "C" void kernel_launch(void* const* d_in, const int* in_sizes, int n_in,
                              void* d_out, int out_size, void* d_ws, size_t ws_size,
                              hipStream_t stream) {
    const float* hidden = (const float*)d_in[0];
    const int* pos = (const int*)d_in[1];
    const float* wq = (const float*)d_in[2];
    const float* wk = (const float*)d_in[3];
    const float* wv = (const float*)d_in[4];
    const float* wo = (const float*)d_in[5];
    float* out = (float*)d_out;

    char* ws = (char*)d_ws;
    size_t off = 0;
    auto alloc = [&](size_t bytes) { char* p = ws + off; off += (bytes + 255) & ~255ULL; return p; };
    u16* Xb   = (u16*)alloc(8388608ULL * 2);     // hidden bf16 [4096][2048]
    u16* WB   = (u16*)alloc(6291456ULL * 2);     // [wq;wk;wv] bf16 [3072][2048]
    u16* WoB  = (u16*)alloc(4194304ULL * 2);     // wo bf16 [2048][2048]
    float* QKV = (float*)alloc(12582912ULL * 4); // [4096][3072] f32
    u16* Qb   = (u16*)alloc(8388608ULL * 2);     // [B*16][2048][128]
    u16* Kb   = (u16*)alloc(2097152ULL * 2);     // [B*4][2048][128]
    u16* Vb   = (u16*)alloc(2097152ULL * 2);
    u16* Ab   = (u16*)alloc(8388608ULL * 2);     // attn out bf16 [4096][2048]
    float* ctab = (float*)alloc(262144ULL * 4);
    float* stab = (float*)alloc(262144ULL * 4);

    cast_f32_bf16<<<8192, 256, 0, stream>>>(hidden, Xb, 2097152);
    cast_f32_bf16<<<4096, 256, 0, stream>>>(wq, WB, 1048576);
    cast_f32_bf16<<<1024, 256, 0, stream>>>(wk, WB + 4194304, 262144);
    cast_f32_bf16<<<1024, 256, 0, stream>>>(wv, WB + 5242880, 262144);
    cast_f32_bf16<<<4096, 256, 0, stream>>>(wo, WoB, 1048576);
    rope_table_k<<<1024, 256, 0, stream>>>(pos, ctab, stab);
    gemm_bt<<<dim3(24, 32), 256, 0, stream>>>(Xb, WB, QKV, 4096, 3072, 2048);
    rope_scatter_k<<<dim3(12, 4096), 256, 0, stream>>>(QKV, ctab, stab, Qb, Kb, Vb);
    attn_k<<<dim3(32, 32), 128, 0, stream>>>(Qb, Kb, Vb, Ab);
    gemm_bt<<<dim3(16, 32), 256, 0, stream>>>(Ab, WoB, out, 4096, 2048, 2048);
}

// Round 12
// 292.949 us; speedup vs baseline: 1.4440x; 1.4440x over previous
//
#include <hip/hip_runtime.h>
#include <hip/hip_bf16.h>
#include <cstdint>

typedef unsigned short u16;
typedef __attribute__((ext_vector_type(4))) float f32x4;
typedef __attribute__((ext_vector_type(8))) short s16x8;
typedef __attribute__((ext_vector_type(4))) unsigned int u32x4;
typedef __attribute__((ext_vector_type(2))) unsigned int u32x2;
typedef __attribute__((ext_vector_type(4))) unsigned short u16x4;

#define MFMA16(a, b, c) __builtin_amdgcn_mfma_f32_16x16x32_bf16(a, b, c, 0, 0, 0)
#define GLOAD16(g, l) __builtin_amdgcn_global_load_lds((const __attribute__((address_space(1))) void*)(g), (__attribute__((address_space(3))) void*)(l), 16, 0, 0)

__device__ __forceinline__ u16 f2bf(float f) {
    union { float f; uint32_t u; } v{f};
    uint32_t r = v.u + 0x7FFF + ((v.u >> 16) & 1);
    return (u16)(r >> 16);
}

// ---------------- cast fp32 -> bf16 (vector x4) ----------------
__global__ void cast_f32_bf16(const float* __restrict__ in, u16* __restrict__ out, int n4) {
    int i = blockIdx.x * 256 + threadIdx.x;
    if (i >= n4) return;
    float4 f = ((const float4*)in)[i];
    u16x4 o = { f2bf(f.x), f2bf(f.y), f2bf(f.z), f2bf(f.w) };
    ((u16x4*)out)[i] = o;
}

// ---------------- RoPE cos/sin table: [B*S][64] ----------------
__global__ void rope_table_k(const int* __restrict__ pos, float* __restrict__ ct, float* __restrict__ st) {
    int i = blockIdx.x * 256 + threadIdx.x;  // B*S*64 = 262144
    int j = i & 63;
    int bs = i >> 6;
    float p = (float)pos[bs];
    float invf = powf(10000.0f, -(float)j * (1.0f / 64.0f));
    float ang = p * invf;
    ct[i] = cosf(ang);
    st[i] = sinf(ang);
}

// ---------------- GEMM C = A @ B^T (bf16 in, f32 out), m97-style + XCD swizzle ----------------
// 128x128 tile, BK=64, 4 waves, global_load_lds staging with pre-swizzled global src.
// blockIdx remapped so consecutive M-tiles co-reside on one XCD's L2 (T1; nwg%8==0).
__global__ __launch_bounds__(256) void gemm_bt(const u16* __restrict__ A, const u16* __restrict__ Bw,
                                               float* __restrict__ C, int M, int N, int K) {
    __shared__ u16 As[128 * 64];
    __shared__ u16 Bs[128 * 64];
    const int tid = threadIdx.x;
    const int lane = tid & 63, wid = tid >> 6;
    const int g = lane >> 4, r = lane & 15;

    // XCD-aware swizzle (bijective when nwg % 8 == 0)
    const int gx = gridDim.x, nwg = gx * gridDim.y;
    int lid = blockIdx.y * gx + blockIdx.x;
    int swz = (lid % 8) * (nwg / 8) + lid / 8;
    const int bxi = swz % gx, byi = swz / gx;

    const size_t bm = (size_t)byi * 128, bn = (size_t)bxi * 128;
    const int wr = (wid >> 1) * 64, wc = (wid & 1) * 64;

    const int srow = wid * 32 + (lane >> 3);
    const int schunk = (lane & 7) ^ ((lane >> 3) & 7);
    const u16* aSrc = A + (bm + srow) * (size_t)K + schunk * 8;
    const u16* bSrc = Bw + (bn + srow) * (size_t)K + schunk * 8;
    u16* aDst = As + wid * 2048;  // 32 rows * 64
    u16* bDst = Bs + wid * 2048;

    f32x4 acc[4][4] = {};
    for (int kt = 0; kt < K; kt += 64) {
#pragma unroll
        for (int j = 0; j < 4; ++j) {
            GLOAD16(aSrc + (size_t)(j * 8) * K + kt, aDst + j * 512);
            GLOAD16(bSrc + (size_t)(j * 8) * K + kt, bDst + j * 512);
        }
        __syncthreads();
        s16x8 af[4][2], bfr[4][2];
#pragma unroll
        for (int m = 0; m < 4; ++m)
#pragma unroll
            for (int kk = 0; kk < 2; ++kk) {
                int rowa = wr + m * 16 + r;
                af[m][kk] = *(const s16x8*)(As + rowa * 64 + (((kk * 4 + g) ^ (rowa & 7)) << 3));
                int rowb = wc + m * 16 + r;
                bfr[m][kk] = *(const s16x8*)(Bs + rowb * 64 + (((kk * 4 + g) ^ (rowb & 7)) << 3));
            }
#pragma unroll
        for (int m = 0; m < 4; ++m)
#pragma unroll
            for (int n = 0; n < 4; ++n) {
                acc[m][n] = MFMA16(af[m][0], bfr[n][0], acc[m][n]);
                acc[m][n] = MFMA16(af[m][1], bfr[n][1], acc[m][n]);
            }
        __syncthreads();
    }
#pragma unroll
    for (int m = 0; m < 4; ++m)
#pragma unroll
        for (int n = 0; n < 4; ++n)
#pragma unroll
            for (int i = 0; i < 4; ++i) {
                size_t row = bm + wr + m * 16 + g * 4 + i;
                size_t col = bn + wc + n * 16 + r;
                C[row * N + col] = acc[m][n][i];
            }
}

// ---------------- RoPE + scatter QKV f32 -> Qb/Kb/Vb bf16 (head-major) ----------------
__global__ void rope_scatter_k(const float* __restrict__ qkv, const float* __restrict__ ct,
                               const float* __restrict__ st, u16* __restrict__ Qb,
                               u16* __restrict__ Kb, u16* __restrict__ Vb) {
    int bs = blockIdx.y;
    int col = blockIdx.x * 256 + threadIdx.x;
    int b = bs >> 11, s = bs & 2047;
    const float* rowp = qkv + (size_t)bs * 3072;
    float x = rowp[col];
    int d = col & 127;
    if (col >= 2560) {
        int h = (col - 2560) >> 7;
        Vb[(((size_t)(b * 4 + h) * 2048 + s) << 7) + d] = f2bf(x);
    } else {
        int j = d & 63;
        float c = ct[(bs << 6) + j], sn = st[(bs << 6) + j];
        float other = rowp[(col & ~127) + (d ^ 64)];
        float res = (d < 64) ? (x * c - other * sn) : (x * c + other * sn);
        if (col < 2048) {
            int h = col >> 7;
            Qb[(((size_t)(b * 16 + h) * 2048 + s) << 7) + d] = f2bf(res);
        } else {
            int h = (col - 2048) >> 7;
            Kb[(((size_t)(b * 4 + h) * 2048 + s) << 7) + d] = f2bf(res);
        }
    }
}

// ---------------- causal flash attention (round-10 version, verbatim revert) ----------------
// grid: (S/128, B*NQ). 4 waves; wave w handles rows {q0+w*16..+15} (frag 0) and
// {q0+64+w*16..+15} (frag 1). KV tile = 64. Tile t's K/V held in REGISTERS (loaded
// during tile t-1's compute); loop top: barrier -> reg->LDS write -> barrier ->
// issue t+1 global loads (hidden under compute) -> compute.
__global__ __launch_bounds__(256, 2) void attn_k(const u16* __restrict__ Qb, const u16* __restrict__ Kb,
                                                 const u16* __restrict__ Vb, u16* __restrict__ Ob) {
    __shared__ char smem[49152];
    u16* Ksh = (u16*)smem;              // 16KB [64][128], chunk^=(row&7)
    u16* Vts = (u16*)(smem + 16384);    // 16KB [128][64], chunk^=(d&7)^((d>>3)&7)
    char* Pall = smem + 32768;          // 16KB: 8 x 2KB per (wave,frag)
    const int tid = threadIdx.x;
    const int lane = tid & 63, w = tid >> 6;
    const int g = lane >> 4, r = lane & 15;
    const int bh = blockIdx.y;
    const int b = bh >> 4, h = bh & 15;
    const int hkv = h >> 2;
    const int qblk = gridDim.x - 1 - blockIdx.x;   // heavy blocks first
    const int q0 = qblk * 128;
    const u16* Qh = Qb + ((size_t)(b * 16 + h) << 18);
    const u16* Kh = Kb + ((size_t)(b * 4 + hkv) << 18);
    const u16* Vh = Vb + ((size_t)(b * 4 + hkv) << 18);

    s16x8 qf[2][4];
#pragma unroll
    for (int qq = 0; qq < 2; ++qq)
#pragma unroll
        for (int c = 0; c < 4; ++c)
            qf[qq][c] = *(const s16x8*)(Qh + (size_t)(q0 + qq * 64 + w * 16 + r) * 128 + c * 32 + g * 8);

    f32x4 o[2][8] = {};              // per frag O^T: col q=r, row d=dsb*16+g*4+i
    float mrun[2] = {-1e30f, -1e30f};
    float lrun[2] = {0.f, 0.f};
    const int fmax[2] = { q0 + w * 16 + 15, q0 + 64 + w * 16 + 15 };

    const int ntiles = 2 * qblk + 2;
    const int krow0 = tid >> 4, kch = tid & 15;
    const int vdc = tid & 15, vkvp = tid >> 4;

    // prefetch tile 0 into registers
    u32x4 kpr[4], var[2], vbr[2];
#pragma unroll
    for (int it = 0; it < 4; ++it)
        kpr[it] = *(const u32x4*)(Kh + (size_t)(krow0 + it * 16) * 128 + kch * 8);
#pragma unroll
    for (int it = 0; it < 2; ++it) {
        int kv2 = (vkvp + it * 16) * 2;
        var[it] = *(const u32x4*)(Vh + (size_t)kv2 * 128 + vdc * 8);
        vbr[it] = *(const u32x4*)(Vh + (size_t)(kv2 + 1) * 128 + vdc * 8);
    }

    for (int t = 0; t < ntiles; ++t) {
        const int kv0 = t * 64;
        __syncthreads();
        // write K tile from regs
#pragma unroll
        for (int it = 0; it < 4; ++it) {
            int row = krow0 + it * 16;
            *(u32x4*)((char*)Ksh + row * 256 + ((kch ^ (row & 7)) << 4)) = kpr[it];
        }
        // write V transposed from regs
#pragma unroll
        for (int it = 0; it < 2; ++it) {
            int kv2 = (vkvp + it * 16) * 2;
            const u16* p0 = (const u16*)&var[it];
            const u16* p1 = (const u16*)&vbr[it];
#pragma unroll
            for (int j = 0; j < 8; ++j) {
                int d = vdc * 8 + j;
                unsigned int val = (unsigned int)p0[j] | ((unsigned int)p1[j] << 16);
                *(unsigned int*)((char*)Vts +
                    ((d * 128 + kv2 * 2) ^ ((((d & 7) ^ ((d >> 3) & 7))) << 4))) = val;
            }
        }
        __syncthreads();
        // issue next tile's global loads (latency hidden under compute below)
        if (t + 1 < ntiles) {
            const int kn = kv0 + 64;
#pragma unroll
            for (int it = 0; it < 4; ++it)
                kpr[it] = *(const u32x4*)(Kh + (size_t)(kn + krow0 + it * 16) * 128 + kch * 8);
#pragma unroll
            for (int it = 0; it < 2; ++it) {
                int kv2 = kn + (vkvp + it * 16) * 2;
                var[it] = *(const u32x4*)(Vh + (size_t)kv2 * 128 + vdc * 8);
                vbr[it] = *(const u32x4*)(Vh + (size_t)(kv2 + 1) * 128 + vdc * 8);
            }
        }
        // ---- QK^T: shared K fragments feed both q-frags ----
        f32x4 st4[2][4];
#pragma unroll
        for (int ts = 0; ts < 4; ++ts) {
            int row = ts * 16 + r;
            s16x8 kf[4];
#pragma unroll
            for (int c = 0; c < 4; ++c)
                kf[c] = *(const s16x8*)((const char*)Ksh + row * 256 + (((c * 4 + g) ^ (row & 7)) << 4));
            f32x4 a0 = {}, a1 = {};
            if (kv0 <= fmax[0])
#pragma unroll
                for (int c = 0; c < 4; ++c) a0 = MFMA16(kf[c], qf[0][c], a0);
            if (kv0 <= fmax[1])
#pragma unroll
                for (int c = 0; c < 4; ++c) a1 = MFMA16(kf[c], qf[1][c], a1);
            st4[0][ts] = a0;
            st4[1][ts] = a1;
        }
        // ---- per-frag online softmax + P write ----
#pragma unroll
        for (int qq = 0; qq < 2; ++qq) {
            if (kv0 > fmax[qq]) continue;   // wave-uniform, no barriers inside
            const int qg = q0 + qq * 64 + w * 16 + r;
            float sv[16];
            float mtile = -1e30f;
#pragma unroll
            for (int ts = 0; ts < 4; ++ts)
#pragma unroll
                for (int i = 0; i < 4; ++i) {
                    int kvg = kv0 + ts * 16 + g * 4 + i;
                    float s = st4[qq][ts][i] * 0.08838834764831845f;
                    s = (kvg > qg) ? -1e30f : s;
                    sv[ts * 4 + i] = s;
                    mtile = fmaxf(mtile, s);
                }
            mtile = fmaxf(mtile, __shfl_xor(mtile, 16));
            mtile = fmaxf(mtile, __shfl_xor(mtile, 32));
            float mnew = fmaxf(mrun[qq], mtile);
            float corr = __expf(mrun[qq] - mnew);
            float psum = 0.f;
            unsigned int pw[8];
#pragma unroll
            for (int ts = 0; ts < 4; ++ts) {
                float p0 = __expf(sv[ts * 4 + 0] - mnew);
                float p1 = __expf(sv[ts * 4 + 1] - mnew);
                float p2 = __expf(sv[ts * 4 + 2] - mnew);
                float p3 = __expf(sv[ts * 4 + 3] - mnew);
                psum += (p0 + p1) + (p2 + p3);
                pw[ts * 2 + 0] = (unsigned int)f2bf(p0) | ((unsigned int)f2bf(p1) << 16);
                pw[ts * 2 + 1] = (unsigned int)f2bf(p2) | ((unsigned int)f2bf(p3) << 16);
            }
            psum += __shfl_xor(psum, 16);
            psum += __shfl_xor(psum, 32);
            lrun[qq] = lrun[qq] * corr + psum;
            mrun[qq] = mnew;
#pragma unroll
            for (int dsb = 0; dsb < 8; ++dsb)
#pragma unroll
                for (int i = 0; i < 4; ++i) o[qq][dsb][i] *= corr;
            char* pbase = Pall + (w * 2 + qq) * 2048;
#pragma unroll
            for (int ts = 0; ts < 4; ++ts) {
                int chunk = (ts * 2 + (g >> 1)) ^ (r & 7);
                u32x2 val = { pw[ts * 2], pw[ts * 2 + 1] };
                *(u32x2*)(pbase + r * 128 + chunk * 16 + (g & 1) * 8) = val;
            }
        }
        asm volatile("s_waitcnt lgkmcnt(0)" ::: "memory");
        // ---- PV: shared V fragments feed both q-frags ----
#pragma unroll
        for (int c = 0; c < 2; ++c) {
            s16x8 vf[8];
#pragma unroll
            for (int dsb = 0; dsb < 8; ++dsb) {
                int d = dsb * 16 + r;
                vf[dsb] = *(const s16x8*)((const char*)Vts + d * 128 +
                    ((((c * 4 + g) ^ (d & 7) ^ ((d >> 3) & 7))) << 4));
            }
#pragma unroll
            for (int qq = 0; qq < 2; ++qq) {
                if (kv0 > fmax[qq]) continue;
                s16x8 pf = *(const s16x8*)(Pall + (w * 2 + qq) * 2048 + r * 128 +
                                           (((c * 4 + g) ^ (r & 7)) << 4));
#pragma unroll
                for (int dsb = 0; dsb < 8; ++dsb)
                    o[qq][dsb] = MFMA16(vf[dsb], pf, o[qq][dsb]);
            }
        }
    }
    // ---- epilogue: normalize, per-(wave,frag) LDS transpose, coalesced store ----
    __syncthreads();
#pragma unroll
    for (int qq = 0; qq < 2; ++qq) {
        float linv = 1.0f / lrun[qq];
        char* obase = smem + (w << 13) + (qq << 12);   // 4KB: [16 q][128 d] bf16
#pragma unroll
        for (int dsb = 0; dsb < 8; ++dsb)
#pragma unroll
            for (int i = 0; i < 4; ++i) {
                int d = dsb * 16 + g * 4 + i;
                *(u16*)(obase + r * 256 + d * 2) = f2bf(o[qq][dsb][i] * linv);
            }
    }
    asm volatile("s_waitcnt lgkmcnt(0)" ::: "memory");
    const int rr = lane >> 2, cbo = (lane & 3) * 32;
#pragma unroll
    for (int qq = 0; qq < 2; ++qq) {
        char* obase = smem + (w << 13) + (qq << 12);
        size_t oidx = ((size_t)b * 2048 + q0 + qq * 64 + w * 16 + rr) * 2048 + h * 128 + cbo;
#pragma unroll
        for (int p = 0; p < 4; ++p) {
            u32x4 vv = *(const u32x4*)(obase + rr * 256 + cbo * 2 + p * 16);
            *(u32x4*)(Ob + oidx + p * 8) = vv;
        }
    }
}

extern "C" void kernel_launch(void* const* d_in, const int* in_sizes, int n_in,
                              void* d_out, int out_size, void* d_ws, size_t ws_size,
                              hipStream_t stream) {
    const float* hidden = (const float*)d_in[0];
    const int* pos = (const int*)d_in[1];
    const float* wq = (const float*)d_in[2];
    const float* wk = (const float*)d_in[3];
    const float* wv = (const float*)d_in[4];
    const float* wo = (const float*)d_in[5];
    float* out = (float*)d_out;

    char* ws = (char*)d_ws;
    size_t off = 0;
    auto alloc = [&](size_t bytes) { char* p = ws + off; off += (bytes + 255) & ~255ULL; return p; };
    u16* Xb   = (u16*)alloc(8388608ULL * 2);     // hidden bf16 [4096][2048]
    u16* WB   = (u16*)alloc(6291456ULL * 2);     // [wq;wk;wv] bf16 [3072][2048]
    u16* WoB  = (u16*)alloc(4194304ULL * 2);     // wo bf16 [2048][2048]
    float* QKV = (float*)alloc(12582912ULL * 4); // [4096][3072] f32
    u16* Qb   = (u16*)alloc(8388608ULL * 2);     // [B*16][2048][128]
    u16* Kb   = (u16*)alloc(2097152ULL * 2);     // [B*4][2048][128]
    u16* Vb   = (u16*)alloc(2097152ULL * 2);
    u16* Ab   = (u16*)alloc(8388608ULL * 2);     // attn out bf16 [4096][2048]
    float* ctab = (float*)alloc(262144ULL * 4);
    float* stab = (float*)alloc(262144ULL * 4);

    cast_f32_bf16<<<8192, 256, 0, stream>>>(hidden, Xb, 2097152);
    cast_f32_bf16<<<4096, 256, 0, stream>>>(wq, WB, 1048576);
    cast_f32_bf16<<<1024, 256, 0, stream>>>(wk, WB + 4194304, 262144);
    cast_f32_bf16<<<1024, 256, 0, stream>>>(wv, WB + 5242880, 262144);
    cast_f32_bf16<<<4096, 256, 0, stream>>>(wo, WoB, 1048576);
    rope_table_k<<<1024, 256, 0, stream>>>(pos, ctab, stab);
    gemm_bt<<<dim3(24, 32), 256, 0, stream>>>(Xb, WB, QKV, 4096, 3072, 2048);
    rope_scatter_k<<<dim3(12, 4096), 256, 0, stream>>>(QKV, ctab, stab, Qb, Kb, Vb);
    attn_k<<<dim3(16, 32), 256, 0, stream>>>(Qb, Kb, Vb, Ab);
    gemm_bt<<<dim3(16, 32), 256, 0, stream>>>(Ab, WoB, out, 4096, 2048, 2048);
}

// Round 13
// 263.849 us; speedup vs baseline: 1.6033x; 1.1103x over previous
//
#include <hip/hip_runtime.h>
#include <hip/hip_bf16.h>
#include <cstdint>

typedef unsigned short u16;
typedef __attribute__((ext_vector_type(4))) float f32x4;
typedef __attribute__((ext_vector_type(8))) short s16x8;
typedef __attribute__((ext_vector_type(4))) unsigned int u32x4;
typedef __attribute__((ext_vector_type(2))) unsigned int u32x2;
typedef __attribute__((ext_vector_type(4))) unsigned short u16x4;

#define MFMA16(a, b, c) __builtin_amdgcn_mfma_f32_16x16x32_bf16(a, b, c, 0, 0, 0)
#define GLOAD16(g, l) __builtin_amdgcn_global_load_lds((const __attribute__((address_space(1))) void*)(g), (__attribute__((address_space(3))) void*)(l), 16, 0, 0)

__device__ __forceinline__ u16 f2bf(float f) {
    union { float f; uint32_t u; } v{f};
    uint32_t r = v.u + 0x7FFF + ((v.u >> 16) & 1);
    return (u16)(r >> 16);
}

// ---------------- cast fp32 -> bf16 (vector x4) ----------------
__global__ void cast_f32_bf16(const float* __restrict__ in, u16* __restrict__ out, int n4) {
    int i = blockIdx.x * 256 + threadIdx.x;
    if (i >= n4) return;
    float4 f = ((const float4*)in)[i];
    u16x4 o = { f2bf(f.x), f2bf(f.y), f2bf(f.z), f2bf(f.w) };
    ((u16x4*)out)[i] = o;
}

// ---------------- RoPE cos/sin table: [B*S][64] ----------------
__global__ void rope_table_k(const int* __restrict__ pos, float* __restrict__ ct, float* __restrict__ st) {
    int i = blockIdx.x * 256 + threadIdx.x;  // B*S*64 = 262144
    int j = i & 63;
    int bs = i >> 6;
    float p = (float)pos[bs];
    float invf = powf(10000.0f, -(float)j * (1.0f / 64.0f));
    float ang = p * invf;
    ct[i] = cosf(ang);
    st[i] = sinf(ang);
}

// ---------------- GEMM C = A @ B^T (bf16 in, f32 out), m97-style + XCD swizzle ----------------
__global__ __launch_bounds__(256) void gemm_bt(const u16* __restrict__ A, const u16* __restrict__ Bw,
                                               float* __restrict__ C, int M, int N, int K) {
    __shared__ u16 As[128 * 64];
    __shared__ u16 Bs[128 * 64];
    const int tid = threadIdx.x;
    const int lane = tid & 63, wid = tid >> 6;
    const int g = lane >> 4, r = lane & 15;

    // XCD-aware swizzle (bijective when nwg % 8 == 0)
    const int gx = gridDim.x, nwg = gx * gridDim.y;
    int lid = blockIdx.y * gx + blockIdx.x;
    int swz = (lid % 8) * (nwg / 8) + lid / 8;
    const int bxi = swz % gx, byi = swz / gx;

    const size_t bm = (size_t)byi * 128, bn = (size_t)bxi * 128;
    const int wr = (wid >> 1) * 64, wc = (wid & 1) * 64;

    const int srow = wid * 32 + (lane >> 3);
    const int schunk = (lane & 7) ^ ((lane >> 3) & 7);
    const u16* aSrc = A + (bm + srow) * (size_t)K + schunk * 8;
    const u16* bSrc = Bw + (bn + srow) * (size_t)K + schunk * 8;
    u16* aDst = As + wid * 2048;  // 32 rows * 64
    u16* bDst = Bs + wid * 2048;

    f32x4 acc[4][4] = {};
    for (int kt = 0; kt < K; kt += 64) {
#pragma unroll
        for (int j = 0; j < 4; ++j) {
            GLOAD16(aSrc + (size_t)(j * 8) * K + kt, aDst + j * 512);
            GLOAD16(bSrc + (size_t)(j * 8) * K + kt, bDst + j * 512);
        }
        __syncthreads();
        s16x8 af[4][2], bfr[4][2];
#pragma unroll
        for (int m = 0; m < 4; ++m)
#pragma unroll
            for (int kk = 0; kk < 2; ++kk) {
                int rowa = wr + m * 16 + r;
                af[m][kk] = *(const s16x8*)(As + rowa * 64 + (((kk * 4 + g) ^ (rowa & 7)) << 3));
                int rowb = wc + m * 16 + r;
                bfr[m][kk] = *(const s16x8*)(Bs + rowb * 64 + (((kk * 4 + g) ^ (rowb & 7)) << 3));
            }
#pragma unroll
        for (int m = 0; m < 4; ++m)
#pragma unroll
            for (int n = 0; n < 4; ++n) {
                acc[m][n] = MFMA16(af[m][0], bfr[n][0], acc[m][n]);
                acc[m][n] = MFMA16(af[m][1], bfr[n][1], acc[m][n]);
            }
        __syncthreads();
    }
#pragma unroll
    for (int m = 0; m < 4; ++m)
#pragma unroll
        for (int n = 0; n < 4; ++n)
#pragma unroll
            for (int i = 0; i < 4; ++i) {
                size_t row = bm + wr + m * 16 + g * 4 + i;
                size_t col = bn + wc + n * 16 + r;
                C[row * N + col] = acc[m][n][i];
            }
}

// ---------------- RoPE + scatter QKV f32 -> Qb/Kb/Vb bf16 (head-major) ----------------
__global__ void rope_scatter_k(const float* __restrict__ qkv, const float* __restrict__ ct,
                               const float* __restrict__ st, u16* __restrict__ Qb,
                               u16* __restrict__ Kb, u16* __restrict__ Vb) {
    int bs = blockIdx.y;
    int col = blockIdx.x * 256 + threadIdx.x;
    int b = bs >> 11, s = bs & 2047;
    const float* rowp = qkv + (size_t)bs * 3072;
    float x = rowp[col];
    int d = col & 127;
    if (col >= 2560) {
        int h = (col - 2560) >> 7;
        Vb[(((size_t)(b * 4 + h) * 2048 + s) << 7) + d] = f2bf(x);
    } else {
        int j = d & 63;
        float c = ct[(bs << 6) + j], sn = st[(bs << 6) + j];
        float other = rowp[(col & ~127) + (d ^ 64)];
        float res = (d < 64) ? (x * c - other * sn) : (x * c + other * sn);
        if (col < 2048) {
            int h = col >> 7;
            Qb[(((size_t)(b * 16 + h) * 2048 + s) << 7) + d] = f2bf(res);
        } else {
            int h = (col - 2048) >> 7;
            Kb[(((size_t)(b * 4 + h) * 2048 + s) << 7) + d] = f2bf(res);
        }
    }
}

// ---------------- causal flash attention (round-10/12 math + balanced CU pairing) ----------------
// grid: (16, 32) = 512 blocks. Work per q-tile = 2*qblk+2 tile-steps. Remap linear
// block id so ids i and i+256 (which co-reside on one CU under round-robin dispatch)
// get COMPLEMENTARY qblk (sum=15): every CU pair totals 36 steps (was up to 64).
// Heavy half (qblk 8..15) occupies the first 256 ids. Kernel math unchanged.
__global__ __launch_bounds__(256, 2) void attn_k(const u16* __restrict__ Qb, const u16* __restrict__ Kb,
                                                 const u16* __restrict__ Vb, u16* __restrict__ Ob) {
    __shared__ char smem[49152];
    u16* Ksh = (u16*)smem;              // 16KB [64][128], chunk^=(row&7)
    u16* Vts = (u16*)(smem + 16384);    // 16KB [128][64], chunk^=(d&7)^((d>>3)&7)
    char* Pall = smem + 32768;          // 16KB: 8 x 2KB per (wave,frag)
    const int tid = threadIdx.x;
    const int lane = tid & 63, w = tid >> 6;
    const int g = lane >> 4, r = lane & 15;

    // balanced complementary remap (bijective over 512)
    const int lid = blockIdx.y * gridDim.x + blockIdx.x;  // 0..511
    const int cpy = lid >> 8, p = lid & 255;
    const int bh = p & 31;
    const int qblk = cpy ? (7 - (p >> 5)) : ((p >> 5) + 8);

    const int b = bh >> 4, h = bh & 15;
    const int hkv = h >> 2;
    const int q0 = qblk * 128;
    const u16* Qh = Qb + ((size_t)(b * 16 + h) << 18);
    const u16* Kh = Kb + ((size_t)(b * 4 + hkv) << 18);
    const u16* Vh = Vb + ((size_t)(b * 4 + hkv) << 18);

    s16x8 qf[2][4];
#pragma unroll
    for (int qq = 0; qq < 2; ++qq)
#pragma unroll
        for (int c = 0; c < 4; ++c)
            qf[qq][c] = *(const s16x8*)(Qh + (size_t)(q0 + qq * 64 + w * 16 + r) * 128 + c * 32 + g * 8);

    f32x4 o[2][8] = {};              // per frag O^T: col q=r, row d=dsb*16+g*4+i
    float mrun[2] = {-1e30f, -1e30f};
    float lrun[2] = {0.f, 0.f};
    const int fmax[2] = { q0 + w * 16 + 15, q0 + 64 + w * 16 + 15 };

    const int ntiles = 2 * qblk + 2;
    const int krow0 = tid >> 4, kch = tid & 15;
    const int vdc = tid & 15, vkvp = tid >> 4;

    // prefetch tile 0 into registers
    u32x4 kpr[4], var[2], vbr[2];
#pragma unroll
    for (int it = 0; it < 4; ++it)
        kpr[it] = *(const u32x4*)(Kh + (size_t)(krow0 + it * 16) * 128 + kch * 8);
#pragma unroll
    for (int it = 0; it < 2; ++it) {
        int kv2 = (vkvp + it * 16) * 2;
        var[it] = *(const u32x4*)(Vh + (size_t)kv2 * 128 + vdc * 8);
        vbr[it] = *(const u32x4*)(Vh + (size_t)(kv2 + 1) * 128 + vdc * 8);
    }

    for (int t = 0; t < ntiles; ++t) {
        const int kv0 = t * 64;
        __syncthreads();
        // write K tile from regs
#pragma unroll
        for (int it = 0; it < 4; ++it) {
            int row = krow0 + it * 16;
            *(u32x4*)((char*)Ksh + row * 256 + ((kch ^ (row & 7)) << 4)) = kpr[it];
        }
        // write V transposed from regs
#pragma unroll
        for (int it = 0; it < 2; ++it) {
            int kv2 = (vkvp + it * 16) * 2;
            const u16* p0 = (const u16*)&var[it];
            const u16* p1 = (const u16*)&vbr[it];
#pragma unroll
            for (int j = 0; j < 8; ++j) {
                int d = vdc * 8 + j;
                unsigned int val = (unsigned int)p0[j] | ((unsigned int)p1[j] << 16);
                *(unsigned int*)((char*)Vts +
                    ((d * 128 + kv2 * 2) ^ ((((d & 7) ^ ((d >> 3) & 7))) << 4))) = val;
            }
        }
        __syncthreads();
        // issue next tile's global loads (latency hidden under compute below)
        if (t + 1 < ntiles) {
            const int kn = kv0 + 64;
#pragma unroll
            for (int it = 0; it < 4; ++it)
                kpr[it] = *(const u32x4*)(Kh + (size_t)(kn + krow0 + it * 16) * 128 + kch * 8);
#pragma unroll
            for (int it = 0; it < 2; ++it) {
                int kv2 = kn + (vkvp + it * 16) * 2;
                var[it] = *(const u32x4*)(Vh + (size_t)kv2 * 128 + vdc * 8);
                vbr[it] = *(const u32x4*)(Vh + (size_t)(kv2 + 1) * 128 + vdc * 8);
            }
        }
        // ---- QK^T: shared K fragments feed both q-frags ----
        f32x4 st4[2][4];
#pragma unroll
        for (int ts = 0; ts < 4; ++ts) {
            int row = ts * 16 + r;
            s16x8 kf[4];
#pragma unroll
            for (int c = 0; c < 4; ++c)
                kf[c] = *(const s16x8*)((const char*)Ksh + row * 256 + (((c * 4 + g) ^ (row & 7)) << 4));
            f32x4 a0 = {}, a1 = {};
            if (kv0 <= fmax[0])
#pragma unroll
                for (int c = 0; c < 4; ++c) a0 = MFMA16(kf[c], qf[0][c], a0);
            if (kv0 <= fmax[1])
#pragma unroll
                for (int c = 0; c < 4; ++c) a1 = MFMA16(kf[c], qf[1][c], a1);
            st4[0][ts] = a0;
            st4[1][ts] = a1;
        }
        // ---- per-frag online softmax + P write ----
#pragma unroll
        for (int qq = 0; qq < 2; ++qq) {
            if (kv0 > fmax[qq]) continue;   // wave-uniform, no barriers inside
            const int qg = q0 + qq * 64 + w * 16 + r;
            float sv[16];
            float mtile = -1e30f;
#pragma unroll
            for (int ts = 0; ts < 4; ++ts)
#pragma unroll
                for (int i = 0; i < 4; ++i) {
                    int kvg = kv0 + ts * 16 + g * 4 + i;
                    float s = st4[qq][ts][i] * 0.08838834764831845f;
                    s = (kvg > qg) ? -1e30f : s;
                    sv[ts * 4 + i] = s;
                    mtile = fmaxf(mtile, s);
                }
            mtile = fmaxf(mtile, __shfl_xor(mtile, 16));
            mtile = fmaxf(mtile, __shfl_xor(mtile, 32));
            float mnew = fmaxf(mrun[qq], mtile);
            float corr = __expf(mrun[qq] - mnew);
            float psum = 0.f;
            unsigned int pw[8];
#pragma unroll
            for (int ts = 0; ts < 4; ++ts) {
                float p0 = __expf(sv[ts * 4 + 0] - mnew);
                float p1 = __expf(sv[ts * 4 + 1] - mnew);
                float p2 = __expf(sv[ts * 4 + 2] - mnew);
                float p3 = __expf(sv[ts * 4 + 3] - mnew);
                psum += (p0 + p1) + (p2 + p3);
                pw[ts * 2 + 0] = (unsigned int)f2bf(p0) | ((unsigned int)f2bf(p1) << 16);
                pw[ts * 2 + 1] = (unsigned int)f2bf(p2) | ((unsigned int)f2bf(p3) << 16);
            }
            psum += __shfl_xor(psum, 16);
            psum += __shfl_xor(psum, 32);
            lrun[qq] = lrun[qq] * corr + psum;
            mrun[qq] = mnew;
#pragma unroll
            for (int dsb = 0; dsb < 8; ++dsb)
#pragma unroll
                for (int i = 0; i < 4; ++i) o[qq][dsb][i] *= corr;
            char* pbase = Pall + (w * 2 + qq) * 2048;
#pragma unroll
            for (int ts = 0; ts < 4; ++ts) {
                int chunk = (ts * 2 + (g >> 1)) ^ (r & 7);
                u32x2 val = { pw[ts * 2], pw[ts * 2 + 1] };
                *(u32x2*)(pbase + r * 128 + chunk * 16 + (g & 1) * 8) = val;
            }
        }
        asm volatile("s_waitcnt lgkmcnt(0)" ::: "memory");
        // ---- PV: shared V fragments feed both q-frags ----
#pragma unroll
        for (int c = 0; c < 2; ++c) {
            s16x8 vf[8];
#pragma unroll
            for (int dsb = 0; dsb < 8; ++dsb) {
                int d = dsb * 16 + r;
                vf[dsb] = *(const s16x8*)((const char*)Vts + d * 128 +
                    ((((c * 4 + g) ^ (d & 7) ^ ((d >> 3) & 7))) << 4));
            }
#pragma unroll
            for (int qq = 0; qq < 2; ++qq) {
                if (kv0 > fmax[qq]) continue;
                s16x8 pf = *(const s16x8*)(Pall + (w * 2 + qq) * 2048 + r * 128 +
                                           (((c * 4 + g) ^ (r & 7)) << 4));
#pragma unroll
                for (int dsb = 0; dsb < 8; ++dsb)
                    o[qq][dsb] = MFMA16(vf[dsb], pf, o[qq][dsb]);
            }
        }
    }
    // ---- epilogue: normalize, per-(wave,frag) LDS transpose, coalesced store ----
    __syncthreads();
#pragma unroll
    for (int qq = 0; qq < 2; ++qq) {
        float linv = 1.0f / lrun[qq];
        char* obase = smem + (w << 13) + (qq << 12);   // 4KB: [16 q][128 d] bf16
#pragma unroll
        for (int dsb = 0; dsb < 8; ++dsb)
#pragma unroll
            for (int i = 0; i < 4; ++i) {
                int d = dsb * 16 + g * 4 + i;
                *(u16*)(obase + r * 256 + d * 2) = f2bf(o[qq][dsb][i] * linv);
            }
    }
    asm volatile("s_waitcnt lgkmcnt(0)" ::: "memory");
    const int rr = lane >> 2, cbo = (lane & 3) * 32;
#pragma unroll
    for (int qq = 0; qq < 2; ++qq) {
        char* obase = smem + (w << 13) + (qq << 12);
        size_t oidx = ((size_t)b * 2048 + q0 + qq * 64 + w * 16 + rr) * 2048 + h * 128 + cbo;
#pragma unroll
        for (int p2 = 0; p2 < 4; ++p2) {
            u32x4 vv = *(const u32x4*)(obase + rr * 256 + cbo * 2 + p2 * 16);
            *(u32x4*)(Ob + oidx + p2 * 8) = vv;
        }
    }
}

extern "C" void kernel_launch(void* const* d_in, const int* in_sizes, int n_in,
                              void* d_out, int out_size, void* d_ws, size_t ws_size,
                              hipStream_t stream) {
    const float* hidden = (const float*)d_in[0];
    const int* pos = (const int*)d_in[1];
    const float* wq = (const float*)d_in[2];
    const float* wk = (const float*)d_in[3];
    const float* wv = (const float*)d_in[4];
    const float* wo = (const float*)d_in[5];
    float* out = (float*)d_out;

    char* ws = (char*)d_ws;
    size_t off = 0;
    auto alloc = [&](size_t bytes) { char* p = ws + off; off += (bytes + 255) & ~255ULL; return p; };
    u16* Xb   = (u16*)alloc(8388608ULL * 2);     // hidden bf16 [4096][2048]
    u16* WB   = (u16*)alloc(6291456ULL * 2);     // [wq;wk;wv] bf16 [3072][2048]
    u16* WoB  = (u16*)alloc(4194304ULL * 2);     // wo bf16 [2048][2048]
    float* QKV = (float*)alloc(12582912ULL * 4); // [4096][3072] f32
    u16* Qb   = (u16*)alloc(8388608ULL * 2);     // [B*16][2048][128]
    u16* Kb   = (u16*)alloc(2097152ULL * 2);     // [B*4][2048][128]
    u16* Vb   = (u16*)alloc(2097152ULL * 2);
    u16* Ab   = (u16*)alloc(8388608ULL * 2);     // attn out bf16 [4096][2048]
    float* ctab = (float*)alloc(262144ULL * 4);
    float* stab = (float*)alloc(262144ULL * 4);

    cast_f32_bf16<<<8192, 256, 0, stream>>>(hidden, Xb, 2097152);
    cast_f32_bf16<<<4096, 256, 0, stream>>>(wq, WB, 1048576);
    cast_f32_bf16<<<1024, 256, 0, stream>>>(wk, WB + 4194304, 262144);
    cast_f32_bf16<<<1024, 256, 0, stream>>>(wv, WB + 5242880, 262144);
    cast_f32_bf16<<<4096, 256, 0, stream>>>(wo, WoB, 1048576);
    rope_table_k<<<1024, 256, 0, stream>>>(pos, ctab, stab);
    gemm_bt<<<dim3(24, 32), 256, 0, stream>>>(Xb, WB, QKV, 4096, 3072, 2048);
    rope_scatter_k<<<dim3(12, 4096), 256, 0, stream>>>(QKV, ctab, stab, Qb, Kb, Vb);
    attn_k<<<dim3(16, 32), 256, 0, stream>>>(Qb, Kb, Vb, Ab);
    gemm_bt<<<dim3(16, 32), 256, 0, stream>>>(Ab, WoB, out, 4096, 2048, 2048);
}

// Round 14
// 249.576 us; speedup vs baseline: 1.6950x; 1.0572x over previous
//
#include <hip/hip_runtime.h>
#include <hip/hip_bf16.h>
#include <cstdint>

typedef unsigned short u16;
typedef __attribute__((ext_vector_type(4))) float f32x4;
typedef __attribute__((ext_vector_type(8))) short s16x8;
typedef __attribute__((ext_vector_type(4))) unsigned int u32x4;
typedef __attribute__((ext_vector_type(2))) unsigned int u32x2;
typedef __attribute__((ext_vector_type(4))) unsigned short u16x4;

#define MFMA16(a, b, c) __builtin_amdgcn_mfma_f32_16x16x32_bf16(a, b, c, 0, 0, 0)
#define GLOAD16(g, l) __builtin_amdgcn_global_load_lds((const __attribute__((address_space(1))) void*)(g), (__attribute__((address_space(3))) void*)(l), 16, 0, 0)

__device__ __forceinline__ u16 f2bf(float f) {
    union { float f; uint32_t u; } v{f};
    uint32_t r = v.u + 0x7FFF + ((v.u >> 16) & 1);
    return (u16)(r >> 16);
}
__device__ __forceinline__ float bf2f(u16 b) {
    union { uint32_t u; float f; } v;
    v.u = ((uint32_t)b) << 16;
    return v.f;
}

// ---------------- cast fp32 -> bf16 (vector x4) ----------------
__global__ void cast_f32_bf16(const float* __restrict__ in, u16* __restrict__ out, int n4) {
    int i = blockIdx.x * 256 + threadIdx.x;
    if (i >= n4) return;
    float4 f = ((const float4*)in)[i];
    u16x4 o = { f2bf(f.x), f2bf(f.y), f2bf(f.z), f2bf(f.w) };
    ((u16x4*)out)[i] = o;
}

// ---------------- RoPE cos/sin table: [B*S][64] ----------------
__global__ void rope_table_k(const int* __restrict__ pos, float* __restrict__ ct, float* __restrict__ st) {
    int i = blockIdx.x * 256 + threadIdx.x;  // B*S*64 = 262144
    int j = i & 63;
    int bs = i >> 6;
    float p = (float)pos[bs];
    float invf = powf(10000.0f, -(float)j * (1.0f / 64.0f));
    float ang = p * invf;
    ct[i] = cosf(ang);
    st[i] = sinf(ang);
}

// ---------------- GEMM C = A @ B^T, m97-style + XCD swizzle ----------------
// FUSE=0: plain f32 C store (O-proj). FUSE=1: QKV path — epilogue applies RoPE and
// scatters bf16 directly to head-major Qb/Kb/Vb (C unused). Block's 128 N-cols =
// one head: bn<16 Q head bn; 16..19 K head bn-16; 20..23 V head bn-20.
template <int FUSE>
__global__ __launch_bounds__(256) void gemm_bt(const u16* __restrict__ A, const u16* __restrict__ Bw,
                                               float* __restrict__ C, int M, int N, int K,
                                               const float* __restrict__ ct, const float* __restrict__ st,
                                               u16* __restrict__ Qb, u16* __restrict__ Kb,
                                               u16* __restrict__ Vb) {
    __shared__ u16 Sh[128 * 128];            // K-loop: As = Sh[0:8K], Bs = Sh[8K:16K] (u16 idx)
    u16* As = Sh;
    u16* Bs = Sh + 8192;
    const int tid = threadIdx.x;
    const int lane = tid & 63, wid = tid >> 6;
    const int g = lane >> 4, r = lane & 15;

    // XCD-aware swizzle (bijective when nwg % 8 == 0)
    const int gx = gridDim.x, nwg = gx * gridDim.y;
    int lid = blockIdx.y * gx + blockIdx.x;
    int swz = (lid % 8) * (nwg / 8) + lid / 8;
    const int bxi = swz % gx, byi = swz / gx;

    const size_t bm = (size_t)byi * 128, bn = (size_t)bxi * 128;
    const int wr = (wid >> 1) * 64, wc = (wid & 1) * 64;

    const int srow = wid * 32 + (lane >> 3);
    const int schunk = (lane & 7) ^ ((lane >> 3) & 7);
    const u16* aSrc = A + (bm + srow) * (size_t)K + schunk * 8;
    const u16* bSrc = Bw + (bn + srow) * (size_t)K + schunk * 8;
    u16* aDst = As + wid * 2048;  // 32 rows * 64
    u16* bDst = Bs + wid * 2048;

    f32x4 acc[4][4] = {};
    for (int kt = 0; kt < K; kt += 64) {
#pragma unroll
        for (int j = 0; j < 4; ++j) {
            GLOAD16(aSrc + (size_t)(j * 8) * K + kt, aDst + j * 512);
            GLOAD16(bSrc + (size_t)(j * 8) * K + kt, bDst + j * 512);
        }
        __syncthreads();
        s16x8 af[4][2], bfr[4][2];
#pragma unroll
        for (int m = 0; m < 4; ++m)
#pragma unroll
            for (int kk = 0; kk < 2; ++kk) {
                int rowa = wr + m * 16 + r;
                af[m][kk] = *(const s16x8*)(As + rowa * 64 + (((kk * 4 + g) ^ (rowa & 7)) << 3));
                int rowb = wc + m * 16 + r;
                bfr[m][kk] = *(const s16x8*)(Bs + rowb * 64 + (((kk * 4 + g) ^ (rowb & 7)) << 3));
            }
#pragma unroll
        for (int m = 0; m < 4; ++m)
#pragma unroll
            for (int n = 0; n < 4; ++n) {
                acc[m][n] = MFMA16(af[m][0], bfr[n][0], acc[m][n]);
                acc[m][n] = MFMA16(af[m][1], bfr[n][1], acc[m][n]);
            }
        __syncthreads();
    }
    if (FUSE == 0) {
#pragma unroll
        for (int m = 0; m < 4; ++m)
#pragma unroll
            for (int n = 0; n < 4; ++n)
#pragma unroll
                for (int i = 0; i < 4; ++i) {
                    size_t row = bm + wr + m * 16 + g * 4 + i;
                    size_t col = bn + wc + n * 16 + r;
                    C[row * N + col] = acc[m][n][i];
                }
        return;
    }
    // ---- FUSE=1 epilogue: acc -> bf16 LDS tile T[128][128] (chunk^=(row&15)) ----
    // (Sh is dead after the trailing K-loop barrier.)
#pragma unroll
    for (int m = 0; m < 4; ++m)
#pragma unroll
        for (int n = 0; n < 4; ++n)
#pragma unroll
            for (int i = 0; i < 4; ++i) {
                int rowl = wr + m * 16 + g * 4 + i;
                int col = wc + n * 16 + r;
                int c4 = col >> 3;
                *(u16*)((char*)Sh + rowl * 256 + (((c4 ^ (rowl & 15))) << 4) + ((col & 7) << 1)) =
                    f2bf(acc[m][n][i]);
            }
    __syncthreads();
    if (tid < 128) {
        const int rowl = tid;
        const size_t tok = bm + rowl;
        const int b = (int)(tok >> 11), s = (int)(tok & 2047);
        const int hb = bxi;
        u16* dst;
        if (hb < 16)      dst = Qb + (((size_t)(b * 16 + hb) * 2048 + s) << 7);
        else if (hb < 20) dst = Kb + (((size_t)(b * 4 + (hb - 16)) * 2048 + s) << 7);
        else              dst = Vb + (((size_t)(b * 4 + (hb - 20)) * 2048 + s) << 7);
        const char* tb = (const char*)Sh + rowl * 256;
        if (hb < 20) {
            const float* ctr = ct + tok * 64;
            const float* str = st + tok * 64;
#pragma unroll
            for (int c4 = 0; c4 < 8; ++c4) {
                u32x4 lo4 = *(const u32x4*)(tb + ((c4 ^ (rowl & 15)) << 4));
                u32x4 hi4 = *(const u32x4*)(tb + (((c4 + 8) ^ (rowl & 15)) << 4));
                const u16* lo = (const u16*)&lo4;
                const u16* hi = (const u16*)&hi4;
                u16x4 o0, o1, o2, o3;
                u16* olo[2] = { (u16*)&o0, (u16*)&o1 };
                u16* ohi[2] = { (u16*)&o2, (u16*)&o3 };
#pragma unroll
                for (int j = 0; j < 8; ++j) {
                    float c = ctr[c4 * 8 + j], sn = str[c4 * 8 + j];
                    float xl = bf2f(lo[j]), xh = bf2f(hi[j]);
                    olo[j >> 2][j & 3] = f2bf(xl * c - xh * sn);
                    ohi[j >> 2][j & 3] = f2bf(xh * c + xl * sn);
                }
                *(u16x4*)(dst + c4 * 8) = o0;
                *(u16x4*)(dst + c4 * 8 + 4) = o1;
                *(u16x4*)(dst + 64 + c4 * 8) = o2;
                *(u16x4*)(dst + 64 + c4 * 8 + 4) = o3;
            }
        } else {
#pragma unroll
            for (int c4 = 0; c4 < 16; ++c4) {
                u32x4 v4 = *(const u32x4*)(tb + ((c4 ^ (rowl & 15)) << 4));
                *(u32x4*)(dst + c4 * 8) = v4;
            }
        }
    }
}

// ---------------- causal flash attention (round-13 version, unchanged) ----------------
__global__ __launch_bounds__(256, 2) void attn_k(const u16* __restrict__ Qb, const u16* __restrict__ Kb,
                                                 const u16* __restrict__ Vb, u16* __restrict__ Ob) {
    __shared__ char smem[49152];
    u16* Ksh = (u16*)smem;              // 16KB [64][128], chunk^=(row&7)
    u16* Vts = (u16*)(smem + 16384);    // 16KB [128][64], chunk^=(d&7)^((d>>3)&7)
    char* Pall = smem + 32768;          // 16KB: 8 x 2KB per (wave,frag)
    const int tid = threadIdx.x;
    const int lane = tid & 63, w = tid >> 6;
    const int g = lane >> 4, r = lane & 15;

    // balanced complementary remap (bijective over 512)
    const int lid = blockIdx.y * gridDim.x + blockIdx.x;  // 0..511
    const int cpy = lid >> 8, p = lid & 255;
    const int bh = p & 31;
    const int qblk = cpy ? (7 - (p >> 5)) : ((p >> 5) + 8);

    const int b = bh >> 4, h = bh & 15;
    const int hkv = h >> 2;
    const int q0 = qblk * 128;
    const u16* Qh = Qb + ((size_t)(b * 16 + h) << 18);
    const u16* Kh = Kb + ((size_t)(b * 4 + hkv) << 18);
    const u16* Vh = Vb + ((size_t)(b * 4 + hkv) << 18);

    s16x8 qf[2][4];
#pragma unroll
    for (int qq = 0; qq < 2; ++qq)
#pragma unroll
        for (int c = 0; c < 4; ++c)
            qf[qq][c] = *(const s16x8*)(Qh + (size_t)(q0 + qq * 64 + w * 16 + r) * 128 + c * 32 + g * 8);

    f32x4 o[2][8] = {};              // per frag O^T: col q=r, row d=dsb*16+g*4+i
    float mrun[2] = {-1e30f, -1e30f};
    float lrun[2] = {0.f, 0.f};
    const int fmax[2] = { q0 + w * 16 + 15, q0 + 64 + w * 16 + 15 };

    const int ntiles = 2 * qblk + 2;
    const int krow0 = tid >> 4, kch = tid & 15;
    const int vdc = tid & 15, vkvp = tid >> 4;

    // prefetch tile 0 into registers
    u32x4 kpr[4], var[2], vbr[2];
#pragma unroll
    for (int it = 0; it < 4; ++it)
        kpr[it] = *(const u32x4*)(Kh + (size_t)(krow0 + it * 16) * 128 + kch * 8);
#pragma unroll
    for (int it = 0; it < 2; ++it) {
        int kv2 = (vkvp + it * 16) * 2;
        var[it] = *(const u32x4*)(Vh + (size_t)kv2 * 128 + vdc * 8);
        vbr[it] = *(const u32x4*)(Vh + (size_t)(kv2 + 1) * 128 + vdc * 8);
    }

    for (int t = 0; t < ntiles; ++t) {
        const int kv0 = t * 64;
        __syncthreads();
        // write K tile from regs
#pragma unroll
        for (int it = 0; it < 4; ++it) {
            int row = krow0 + it * 16;
            *(u32x4*)((char*)Ksh + row * 256 + ((kch ^ (row & 7)) << 4)) = kpr[it];
        }
        // write V transposed from regs
#pragma unroll
        for (int it = 0; it < 2; ++it) {
            int kv2 = (vkvp + it * 16) * 2;
            const u16* p0 = (const u16*)&var[it];
            const u16* p1 = (const u16*)&vbr[it];
#pragma unroll
            for (int j = 0; j < 8; ++j) {
                int d = vdc * 8 + j;
                unsigned int val = (unsigned int)p0[j] | ((unsigned int)p1[j] << 16);
                *(unsigned int*)((char*)Vts +
                    ((d * 128 + kv2 * 2) ^ ((((d & 7) ^ ((d >> 3) & 7))) << 4))) = val;
            }
        }
        __syncthreads();
        // issue next tile's global loads (latency hidden under compute below)
        if (t + 1 < ntiles) {
            const int kn = kv0 + 64;
#pragma unroll
            for (int it = 0; it < 4; ++it)
                kpr[it] = *(const u32x4*)(Kh + (size_t)(kn + krow0 + it * 16) * 128 + kch * 8);
#pragma unroll
            for (int it = 0; it < 2; ++it) {
                int kv2 = kn + (vkvp + it * 16) * 2;
                var[it] = *(const u32x4*)(Vh + (size_t)kv2 * 128 + vdc * 8);
                vbr[it] = *(const u32x4*)(Vh + (size_t)(kv2 + 1) * 128 + vdc * 8);
            }
        }
        // ---- QK^T: shared K fragments feed both q-frags ----
        f32x4 st4[2][4];
#pragma unroll
        for (int ts = 0; ts < 4; ++ts) {
            int row = ts * 16 + r;
            s16x8 kf[4];
#pragma unroll
            for (int c = 0; c < 4; ++c)
                kf[c] = *(const s16x8*)((const char*)Ksh + row * 256 + (((c * 4 + g) ^ (row & 7)) << 4));
            f32x4 a0 = {}, a1 = {};
            if (kv0 <= fmax[0])
#pragma unroll
                for (int c = 0; c < 4; ++c) a0 = MFMA16(kf[c], qf[0][c], a0);
            if (kv0 <= fmax[1])
#pragma unroll
                for (int c = 0; c < 4; ++c) a1 = MFMA16(kf[c], qf[1][c], a1);
            st4[0][ts] = a0;
            st4[1][ts] = a1;
        }
        // ---- per-frag online softmax + P write ----
#pragma unroll
        for (int qq = 0; qq < 2; ++qq) {
            if (kv0 > fmax[qq]) continue;   // wave-uniform, no barriers inside
            const int qg = q0 + qq * 64 + w * 16 + r;
            float sv[16];
            float mtile = -1e30f;
#pragma unroll
            for (int ts = 0; ts < 4; ++ts)
#pragma unroll
                for (int i = 0; i < 4; ++i) {
                    int kvg = kv0 + ts * 16 + g * 4 + i;
                    float s = st4[qq][ts][i] * 0.08838834764831845f;
                    s = (kvg > qg) ? -1e30f : s;
                    sv[ts * 4 + i] = s;
                    mtile = fmaxf(mtile, s);
                }
            mtile = fmaxf(mtile, __shfl_xor(mtile, 16));
            mtile = fmaxf(mtile, __shfl_xor(mtile, 32));
            float mnew = fmaxf(mrun[qq], mtile);
            float corr = __expf(mrun[qq] - mnew);
            float psum = 0.f;
            unsigned int pw[8];
#pragma unroll
            for (int ts = 0; ts < 4; ++ts) {
                float p0 = __expf(sv[ts * 4 + 0] - mnew);
                float p1 = __expf(sv[ts * 4 + 1] - mnew);
                float p2 = __expf(sv[ts * 4 + 2] - mnew);
                float p3 = __expf(sv[ts * 4 + 3] - mnew);
                psum += (p0 + p1) + (p2 + p3);
                pw[ts * 2 + 0] = (unsigned int)f2bf(p0) | ((unsigned int)f2bf(p1) << 16);
                pw[ts * 2 + 1] = (unsigned int)f2bf(p2) | ((unsigned int)f2bf(p3) << 16);
            }
            psum += __shfl_xor(psum, 16);
            psum += __shfl_xor(psum, 32);
            lrun[qq] = lrun[qq] * corr + psum;
            mrun[qq] = mnew;
#pragma unroll
            for (int dsb = 0; dsb < 8; ++dsb)
#pragma unroll
                for (int i = 0; i < 4; ++i) o[qq][dsb][i] *= corr;
            char* pbase = Pall + (w * 2 + qq) * 2048;
#pragma unroll
            for (int ts = 0; ts < 4; ++ts) {
                int chunk = (ts * 2 + (g >> 1)) ^ (r & 7);
                u32x2 val = { pw[ts * 2], pw[ts * 2 + 1] };
                *(u32x2*)(pbase + r * 128 + chunk * 16 + (g & 1) * 8) = val;
            }
        }
        asm volatile("s_waitcnt lgkmcnt(0)" ::: "memory");
        // ---- PV: shared V fragments feed both q-frags ----
#pragma unroll
        for (int c = 0; c < 2; ++c) {
            s16x8 vf[8];
#pragma unroll
            for (int dsb = 0; dsb < 8; ++dsb) {
                int d = dsb * 16 + r;
                vf[dsb] = *(const s16x8*)((const char*)Vts + d * 128 +
                    ((((c * 4 + g) ^ (d & 7) ^ ((d >> 3) & 7))) << 4));
            }
#pragma unroll
            for (int qq = 0; qq < 2; ++qq) {
                if (kv0 > fmax[qq]) continue;
                s16x8 pf = *(const s16x8*)(Pall + (w * 2 + qq) * 2048 + r * 128 +
                                           (((c * 4 + g) ^ (r & 7)) << 4));
#pragma unroll
                for (int dsb = 0; dsb < 8; ++dsb)
                    o[qq][dsb] = MFMA16(vf[dsb], pf, o[qq][dsb]);
            }
        }
    }
    // ---- epilogue: normalize, per-(wave,frag) LDS transpose, coalesced store ----
    __syncthreads();
#pragma unroll
    for (int qq = 0; qq < 2; ++qq) {
        float linv = 1.0f / lrun[qq];
        char* obase = smem + (w << 13) + (qq << 12);   // 4KB: [16 q][128 d] bf16
#pragma unroll
        for (int dsb = 0; dsb < 8; ++dsb)
#pragma unroll
            for (int i = 0; i < 4; ++i) {
                int d = dsb * 16 + g * 4 + i;
                *(u16*)(obase + r * 256 + d * 2) = f2bf(o[qq][dsb][i] * linv);
            }
    }
    asm volatile("s_waitcnt lgkmcnt(0)" ::: "memory");
    const int rr = lane >> 2, cbo = (lane & 3) * 32;
#pragma unroll
    for (int qq = 0; qq < 2; ++qq) {
        char* obase = smem + (w << 13) + (qq << 12);
        size_t oidx = ((size_t)b * 2048 + q0 + qq * 64 + w * 16 + rr) * 2048 + h * 128 + cbo;
#pragma unroll
        for (int p2 = 0; p2 < 4; ++p2) {
            u32x4 vv = *(const u32x4*)(obase + rr * 256 + cbo * 2 + p2 * 16);
            *(u32x4*)(Ob + oidx + p2 * 8) = vv;
        }
    }
}

extern "C" void kernel_launch(void* const* d_in, const int* in_sizes, int n_in,
                              void* d_out, int out_size, void* d_ws, size_t ws_size,
                              hipStream_t stream) {
    const float* hidden = (const float*)d_in[0];
    const int* pos = (const int*)d_in[1];
    const float* wq = (const float*)d_in[2];
    const float* wk = (const float*)d_in[3];
    const float* wv = (const float*)d_in[4];
    const float* wo = (const float*)d_in[5];
    float* out = (float*)d_out;

    char* ws = (char*)d_ws;
    size_t off = 0;
    auto alloc = [&](size_t bytes) { char* p = ws + off; off += (bytes + 255) & ~255ULL; return p; };
    u16* Xb   = (u16*)alloc(8388608ULL * 2);     // hidden bf16 [4096][2048]
    u16* WB   = (u16*)alloc(6291456ULL * 2);     // [wq;wk;wv] bf16 [3072][2048]
    u16* WoB  = (u16*)alloc(4194304ULL * 2);     // wo bf16 [2048][2048]
    u16* Qb   = (u16*)alloc(8388608ULL * 2);     // [B*16][2048][128]
    u16* Kb   = (u16*)alloc(2097152ULL * 2);     // [B*4][2048][128]
    u16* Vb   = (u16*)alloc(2097152ULL * 2);
    u16* Ab   = (u16*)alloc(8388608ULL * 2);     // attn out bf16 [4096][2048]
    float* ctab = (float*)alloc(262144ULL * 4);
    float* stab = (float*)alloc(262144ULL * 4);

    cast_f32_bf16<<<8192, 256, 0, stream>>>(hidden, Xb, 2097152);
    cast_f32_bf16<<<4096, 256, 0, stream>>>(wq, WB, 1048576);
    cast_f32_bf16<<<1024, 256, 0, stream>>>(wk, WB + 4194304, 262144);
    cast_f32_bf16<<<1024, 256, 0, stream>>>(wv, WB + 5242880, 262144);
    cast_f32_bf16<<<4096, 256, 0, stream>>>(wo, WoB, 1048576);
    rope_table_k<<<1024, 256, 0, stream>>>(pos, ctab, stab);
    gemm_bt<1><<<dim3(24, 32), 256, 0, stream>>>(Xb, WB, nullptr, 4096, 3072, 2048,
                                                 ctab, stab, Qb, Kb, Vb);
    attn_k<<<dim3(16, 32), 256, 0, stream>>>(Qb, Kb, Vb, Ab);
    gemm_bt<0><<<dim3(16, 32), 256, 0, stream>>>(Ab, WoB, out, 4096, 2048, 2048,
                                                 nullptr, nullptr, nullptr, nullptr, nullptr);
}